// Round 10
// baseline (187.499 us; speedup 1.0000x reference)
//
#include <hip/hip_runtime.h>

typedef __attribute__((ext_vector_type(4))) float f32x4;
typedef __attribute__((ext_vector_type(8))) __bf16 bf16x8;
typedef __attribute__((ext_vector_type(4))) __bf16 bf16x4;

#define LOG_2PI 1.8378770664093453f

__device__ __forceinline__ float softplus_f(float x) {
  return fmaxf(x, 0.f) + log1pf(expf(-fabsf(x)));
}

__device__ __forceinline__ void barrier_lds_only() {
  asm volatile("s_waitcnt lgkmcnt(0)\n\ts_barrier" ::: "memory");
}

// ---------------- prep: marks_proj (blocks 0..1023) + zero accs (block 1024)
__global__ void prep_kernel(const float* __restrict__ em,
                            const float* __restrict__ Wp,
                            const float* __restrict__ bp,
                            float* __restrict__ mp,
                            float* __restrict__ accs) {
  const int b = blockIdx.x;
  if (b == 1024) {
    if (threadIdx.x < 8) accs[threadIdx.x] = 0.f;
    return;
  }
  const int d = threadIdx.x;
  float s = bp[d];
  const float* emr = em + b * 128;
#pragma unroll 4
  for (int k = 0; k < 128; ++k) s += emr[k] * Wp[k * 128 + d];
  mp[b * 128 + d] = s;
}

// ---------------- intensity: full-pair register prefetch, 2 waves/SIMD ------
// 256 blocks x 8 waves = 2048 waves. Rounds 0..3: traj pair p = r*2048+gw
// (8192 pairs). Round 4: even waves take event pair p = 8192+gw/2 (1024
// pairs) -> heavy/light interleaved within each block (CU-balanced).
// Per round: cvt stg->fr, then issue ALL 32 loads of the next pair into stg
// (128 VGPR staging, pinned by sched_barrier) BEFORE the ~10Kcy hidden loop
// -> load-to-use gap >> HBM latency, stall-free HBM streaming.
__global__ __launch_bounds__(512, 2) void intensity9_kernel(
    const float* __restrict__ z_traj, const float* __restrict__ z_ev,
    const float* __restrict__ W1, const float* __restrict__ b1,
    const float* __restrict__ W2, const float* __restrict__ b2,
    const float* __restrict__ base_i, const float* __restrict__ times,
    float* __restrict__ accs) {
  __shared__ __align__(16) __bf16 w1t[512 * 128];  // 128 KB: W1^T, swizzled
  __shared__ __align__(16) float b1L[512];
  __shared__ __align__(16) float w2L[512];
  __shared__ float red[8][4];

  const int tid = threadIdx.x;
  const int wid = tid >> 6, lid = tid & 63;
  const int g = lid >> 4, q = lid & 15;
  const int gw = blockIdx.x * 8 + wid;
  const int nrounds = (gw & 1) ? 4 : 5;

  f32x4 stg[4][4][2];  // full-pair staging (64 rows), 128 VGPR

#define ZPTR(P) ((P) < 8192 ? z_traj + (size_t)(P) * 8192 \
                            : z_ev + (size_t)((P) - 8192) * 8192)
#define LOADP(ZP)                                                          \
  do {                                                                     \
    _Pragma("unroll") for (int s = 0; s < 4; ++s) {                        \
      const float* rp = (ZP) + (s * 16 + q) * 128 + g * 8;                 \
      _Pragma("unroll") for (int kf = 0; kf < 4; ++kf) {                   \
        stg[s][kf][0] = *(const f32x4*)(rp + kf * 32);                     \
        stg[s][kf][1] = *(const f32x4*)(rp + kf * 32 + 4);                 \
      }                                                                    \
    }                                                                      \
  } while (0)

  // prologue: fire round-0 loads before W staging
  LOADP(ZPTR(gw));

  // ---- one-time W1^T -> LDS (bf16, col-XOR swizzle), b1/W2 -> LDS ----
  {
    const float* wcol = W1 + tid;  // W1[k][tid], row stride 512
    char* wbs = (char*)w1t;
    const int colbase = tid * 256;
    const int sw = (tid & 7) << 4;
#pragma unroll 8
    for (int k = 0; k < 128; k += 2) {
      float a = wcol[(size_t)k * 512];
      float c = wcol[(size_t)(k + 1) * 512];
      union { __bf16 h[2]; unsigned u; } pk;
      pk.h[0] = (__bf16)a;
      pk.h[1] = (__bf16)c;
      *(unsigned*)(wbs + (colbase + ((k * 2) ^ sw))) = pk.u;
    }
    b1L[tid] = b1[tid];
    w2L[tid] = W2[tid];
  }
  const float sbias = b2[0] + base_i[0];
  barrier_lds_only();  // W ready; stg loads remain in flight

  float integral_loc = 0.f, logsum_loc = 0.f, kls = 0.f;
  const char* wb = (const char*)w1t;
  const int wsw = (q & 7) << 4;

#pragma unroll 1
  for (int r = 0; r < nrounds; ++r) {
    const bool traj_r = (r < 4);
    const int p = traj_r ? r * 2048 + gw : 8192 + (gw >> 1);

    // ---- cvt stg -> fr (+ kls) ----
    bf16x8 fr[4][4];
#pragma unroll
    for (int s = 0; s < 4; ++s) {
#pragma unroll
      for (int kf = 0; kf < 4; ++kf) {
        f32x4 a0 = stg[s][kf][0], a1 = stg[s][kf][1];
        if (traj_r) {
          kls += a0[0] * a0[0] + a0[1] * a0[1] + a0[2] * a0[2] + a0[3] * a0[3];
          kls += a1[0] * a1[0] + a1[1] * a1[1] + a1[2] * a1[2] + a1[3] * a1[3];
        }
        bf16x8 f;
#pragma unroll
        for (int j = 0; j < 4; ++j) {
          f[j] = (__bf16)a0[j];
          f[4 + j] = (__bf16)a1[j];
        }
        fr[s][kf] = f;
      }
    }

    // ---- fire next pair's 32 loads (consumed after the hidden loop) ----
    if (r + 1 < nrounds) {
      const int pn = (r + 1 < 4) ? (r + 1) * 2048 + gw : 8192 + (gw >> 1);
      const float* zn = ZPTR(pn);
      LOADP(zn);
    }
    __builtin_amdgcn_sched_barrier(0);  // pin: loads issue before hidden loop

    // ---- hidden loop: 32 c-blocks; each W-frag read feeds 4 MFMA ----
    float rowacc0 = 0.f, rowacc1 = 0.f, rowacc2 = 0.f, rowacc3 = 0.f;
#pragma unroll 2
    for (int c = 0; c < 32; ++c) {
      f32x4 a0 = {}, a1 = {}, a2 = {}, a3 = {};
#pragma unroll
      for (int kf = 0; kf < 4; ++kf) {
        bf16x8 wf = *(const bf16x8*)(wb + c * 4096 + q * 256 +
                                     ((kf * 64 + g * 16) ^ wsw));
        a0 = __builtin_amdgcn_mfma_f32_16x16x32_bf16(wf, fr[0][kf], a0, 0, 0, 0);
        a1 = __builtin_amdgcn_mfma_f32_16x16x32_bf16(wf, fr[1][kf], a1, 0, 0, 0);
        a2 = __builtin_amdgcn_mfma_f32_16x16x32_bf16(wf, fr[2][kf], a2, 0, 0, 0);
        a3 = __builtin_amdgcn_mfma_f32_16x16x32_bf16(wf, fr[3][kf], a3, 0, 0, 0);
      }
      f32x4 bb = *(const f32x4*)&b1L[c * 16 + g * 4];
      f32x4 ww = *(const f32x4*)&w2L[c * 16 + g * 4];
#pragma unroll
      for (int ii = 0; ii < 4; ++ii) {
        rowacc0 += fmaxf(a0[ii] + bb[ii], 0.f) * ww[ii];
        rowacc1 += fmaxf(a1[ii] + bb[ii], 0.f) * ww[ii];
        rowacc2 += fmaxf(a2[ii] + bb[ii], 0.f) * ww[ii];
        rowacc3 += fmaxf(a3[ii] + bb[ii], 0.f) * ww[ii];
      }
    }
    // combine 4 g-groups -> full 512-col row sums
    rowacc0 += __shfl_xor(rowacc0, 16);
    rowacc0 += __shfl_xor(rowacc0, 32);
    rowacc1 += __shfl_xor(rowacc1, 16);
    rowacc1 += __shfl_xor(rowacc1, 32);
    rowacc2 += __shfl_xor(rowacc2, 16);
    rowacc2 += __shfl_xor(rowacc2, 32);
    rowacc3 += __shfl_xor(rowacc3, 16);
    rowacc3 += __shfl_xor(rowacc3, 32);

    // lane lid owns row (p*64 + lid)
    {
      const int s = lid >> 4;
      const float rs = (s == 0) ? rowacc0 : (s == 1) ? rowacc1
                     : (s == 2) ? rowacc2 : rowacc3;
      const float lam = softplus_f(rs + sbias);
      if (traj_r) {
        integral_loc += lam * (times[p + 1] - times[p]) * (1.f / 64.f);
      } else {
        logsum_loc += logf(lam + 1e-8f) * (1.f / 64.f);
      }
    }
  }
#undef LOADP
#undef ZPTR

  // ---- wave reduce 3 accumulators, block reduce, 3 atomics ----
#pragma unroll
  for (int m = 32; m >= 1; m >>= 1) {
    integral_loc += __shfl_xor(integral_loc, m);
    logsum_loc += __shfl_xor(logsum_loc, m);
    kls += __shfl_xor(kls, m);
  }
  if (lid == 0) {
    red[wid][0] = integral_loc;
    red[wid][1] = logsum_loc;
    red[wid][2] = kls;
  }
  __syncthreads();
  if (tid == 0) {
    float I = 0.f, L = 0.f, K = 0.f;
#pragma unroll
    for (int w = 0; w < 8; ++w) {
      I += red[w][0];
      L += red[w][1];
      K += red[w][2];
    }
    atomicAdd(&accs[0], I);
    atomicAdd(&accs[1], L);
    atomicAdd(&accs[3], K);
  }
}

// ---------------- decoder: swapped GEMM1 -> h (LDS) -> swapped GEMM2 -> logp
__global__ __launch_bounds__(512, 2) void decoder2_kernel(
    const float* __restrict__ z,
    const float* __restrict__ Wd1, const float* __restrict__ bd1,
    const float* __restrict__ Wd2, const float* __restrict__ bd2,
    const float* __restrict__ mp, float* __restrict__ recon_acc) {
  __shared__ __align__(16) __bf16 zbuf[2][32 * 128];  // 16 KB
  __shared__ __align__(16) __bf16 hbuf[32 * 512];     // 32 KB
  __shared__ float s_part[32][9];
  __shared__ float red[8];

  const int tid = threadIdx.x;
  const int wid = tid >> 6, lid = tid & 63;
  const int g = lid >> 4, q = lid & 15;
  const int cb = wid * 64;
  const int tile0 = blockIdx.x * 4;

  bf16x8 bw1[4][4];
  f32x4 bd1v[4];
#pragma unroll
  for (int cf = 0; cf < 4; ++cf) {
    const int col = cb + cf * 16 + q;
#pragma unroll
    for (int i = 0; i < 4; ++i) bd1v[cf][i] = bd1[cb + cf * 16 + g * 4 + i];
#pragma unroll
    for (int kf = 0; kf < 4; ++kf) {
      bf16x8 f;
#pragma unroll
      for (int j = 0; j < 8; ++j) f[j] = (__bf16)Wd1[(kf * 32 + g * 8 + j) * 512 + col];
      bw1[cf][kf] = f;
    }
  }
  const int dimf = wid * 16 + q;
  bf16x8 bw2[16];
#pragma unroll
  for (int kf2 = 0; kf2 < 16; ++kf2) {
    bf16x8 f;
#pragma unroll
    for (int j = 0; j < 8; ++j) f[j] = (__bf16)Wd2[(kf2 * 32 + g * 8 + j) * 128 + dimf];
    bw2[kf2] = f;
  }
  f32x4 bd2v;
#pragma unroll
  for (int i = 0; i < 4; ++i) bd2v[i] = bd2[wid * 16 + g * 4 + i];

  const int srow = tid >> 4, sk8 = (tid & 15) * 8;
  const int stg_byte = ((srow * 256 + sk8 * 2) ^ ((srow & 7) << 4));
  char* hb = (char*)hbuf;

  float local = 0.f;

  {
    const float* p = z + (size_t)tile0 * 4096 + tid * 8;
    f32x4 r0 = *(const f32x4*)p, r1 = *(const f32x4*)(p + 4);
    bf16x8 v;
#pragma unroll
    for (int j = 0; j < 4; ++j) { v[j] = (__bf16)r0[j]; v[4 + j] = (__bf16)r1[j]; }
    *(bf16x8*)((char*)zbuf[0] + stg_byte) = v;
  }
  f32x4 rA0, rA1, rB0, rB1;
  { const float* p = z + (size_t)(tile0 + 1) * 4096 + tid * 8; rA0 = *(const f32x4*)p; rA1 = *(const f32x4*)(p + 4); }
  { const float* p = z + (size_t)(tile0 + 2) * 4096 + tid * 8; rB0 = *(const f32x4*)p; rB1 = *(const f32x4*)(p + 4); }
  barrier_lds_only();

#define DBODY(T, ZC, RR0, RR1)                                                     \
  do {                                                                             \
    f32x4 acc1[2][4] = {};                                                         \
    char* zc = (char*)zbuf[ZC];                                                    \
    _Pragma("unroll") for (int kf = 0; kf < 4; ++kf) {                             \
      _Pragma("unroll") for (int rf = 0; rf < 2; ++rf) {                           \
        const int row = rf * 16 + q;                                               \
        bf16x8 a = *(const bf16x8*)(zc + ((row * 256 + kf * 64 + g * 16) ^ ((row & 7) << 4))); \
        _Pragma("unroll") for (int cf = 0; cf < 4; ++cf)                           \
          acc1[rf][cf] = __builtin_amdgcn_mfma_f32_16x16x32_bf16(bw1[cf][kf], a, acc1[rf][cf], 0, 0, 0); \
      }                                                                            \
    }                                                                              \
    {                                                                              \
      bf16x8 v;                                                                    \
      _Pragma("unroll") for (int j = 0; j < 4; ++j) { v[j] = (__bf16)RR0[j]; v[4 + j] = (__bf16)RR1[j]; } \
      *(bf16x8*)((char*)zbuf[(ZC) ^ 1] + stg_byte) = v;                            \
    }                                                                              \
    {                                                                              \
      int tl = (T) + 3; if (tl > 3) tl = 3;                                        \
      const float* p = z + (size_t)(tile0 + tl) * 4096 + tid * 8;                  \
      RR0 = *(const f32x4*)p; RR1 = *(const f32x4*)(p + 4);                        \
    }                                                                              \
    _Pragma("unroll") for (int rf = 0; rf < 2; ++rf) {                             \
      const int row = rf * 16 + q;                                                 \
      _Pragma("unroll") for (int cf = 0; cf < 4; ++cf) {                           \
        bf16x4 hv;                                                                 \
        _Pragma("unroll") for (int i = 0; i < 4; ++i)                              \
          hv[i] = (__bf16)fmaxf(acc1[rf][cf][i] + bd1v[cf][i], 0.f);               \
        const int byt = ((row * 1024 + (cb + cf * 16 + g * 4) * 2) ^ ((row & 7) << 4)); \
        *(bf16x4*)(hb + byt) = hv;                                                 \
      }                                                                            \
    }                                                                              \
    barrier_lds_only();                                                            \
    f32x4 acc2[2] = {};                                                            \
    _Pragma("unroll") for (int kf2 = 0; kf2 < 16; ++kf2) {                         \
      _Pragma("unroll") for (int rf2 = 0; rf2 < 2; ++rf2) {                        \
        const int row = rf2 * 16 + q;                                              \
        bf16x8 a = *(const bf16x8*)(hb + ((row * 1024 + kf2 * 64 + g * 16) ^ ((row & 7) << 4))); \
        acc2[rf2] = __builtin_amdgcn_mfma_f32_16x16x32_bf16(bw2[kf2], a, acc2[rf2], 0, 0, 0); \
      }                                                                            \
    }                                                                              \
    const int e = (tile0 + (T)) >> 1;                                              \
    _Pragma("unroll") for (int rf2 = 0; rf2 < 2; ++rf2) {                          \
      float partial = 0.f;                                                         \
      _Pragma("unroll") for (int i = 0; i < 4; ++i) {                              \
        const float xv = mp[e * 128 + wid * 16 + g * 4 + i];                       \
        const float d = xv - (acc2[rf2][i] + bd2v[i]);                             \
        partial += d * d;                                                          \
      }                                                                            \
      partial += __shfl_xor(partial, 16);                                          \
      partial += __shfl_xor(partial, 32);                                          \
      if (lid < 16) s_part[rf2 * 16 + lid][wid] = partial;                         \
    }                                                                              \
    barrier_lds_only();                                                            \
    if (tid < 32) {                                                                \
      float t2 = 0.f;                                                              \
      _Pragma("unroll") for (int w = 0; w < 8; ++w) t2 += s_part[tid][w];          \
      local += (-0.5f * t2 - 0.5f * 128.f * LOG_2PI) * (1.f / 64.f);               \
    }                                                                              \
  } while (0)

#pragma unroll 1
  for (int t = 0; t < 4; t += 2) {
    DBODY(t, 0, rA0, rA1);
    DBODY(t + 1, 1, rB0, rB1);
  }
#undef DBODY

  if (wid == 0) {
#pragma unroll
    for (int m = 16; m >= 1; m >>= 1) local += __shfl_xor(local, m);
    if (lid == 0) atomicAdd(recon_acc, local);
  }
}

// ---------------- finalize --------------------------------------------------
__global__ void finalize_kernel(const float* __restrict__ accs, float* __restrict__ out) {
  // accs: [0]=integral, [1]=log_intensity_sum, [2]=recon, [3]=sum(z_traj^2)
  const float kl = 0.01f * (accs[3] / 67108864.f);  // 8192*64*128
  const float elbo = accs[1] - accs[0] + accs[2] - kl;
  out[0] = -elbo;
}

extern "C" void kernel_launch(void* const* d_in, const int* in_sizes, int n_in,
                              void* d_out, int out_size, void* d_ws, size_t ws_size,
                              hipStream_t stream) {
  const float* event_marks = (const float*)d_in[0];
  const float* z_events = (const float*)d_in[1];
  const float* z_traj = (const float*)d_in[2];
  const float* times = (const float*)d_in[3];
  const float* Wp = (const float*)d_in[4];
  const float* bp = (const float*)d_in[5];
  const float* W1 = (const float*)d_in[6];
  const float* b1 = (const float*)d_in[7];
  const float* W2 = (const float*)d_in[8];
  const float* b2 = (const float*)d_in[9];
  const float* base_i = (const float*)d_in[10];
  const float* Wd1 = (const float*)d_in[11];
  const float* bd1 = (const float*)d_in[12];
  const float* Wd2 = (const float*)d_in[13];
  const float* bd2 = (const float*)d_in[14];

  float* mp = (float*)d_ws;                              // 1024*128 f32
  float* accs = (float*)((char*)d_ws + 1024 * 128 * 4);  // accumulators

  prep_kernel<<<1025, 128, 0, stream>>>(event_marks, Wp, bp, mp, accs);
  intensity9_kernel<<<256, 512, 0, stream>>>(z_traj, z_events, W1, b1, W2, b2,
                                             base_i, times, accs);
  decoder2_kernel<<<512, 512, 0, stream>>>(z_events, Wd1, bd1, Wd2, bd2, mp,
                                           &accs[2]);
  finalize_kernel<<<1, 1, 0, stream>>>(accs, (float*)d_out);
}

// Round 11
// 186.825 us; speedup vs baseline: 1.0036x; 1.0036x over previous
//
#include <hip/hip_runtime.h>

typedef __attribute__((ext_vector_type(4))) float f32x4;
typedef __attribute__((ext_vector_type(8))) __bf16 bf16x8;
typedef __attribute__((ext_vector_type(4))) __bf16 bf16x4;

#define LOG_2PI 1.8378770664093453f

__device__ __forceinline__ float softplus_f(float x) {
  return fmaxf(x, 0.f) + log1pf(expf(-fabsf(x)));
}

__device__ __forceinline__ void barrier_lds_only() {
  asm volatile("s_waitcnt lgkmcnt(0)\n\ts_barrier" ::: "memory");
}

// ---------------- prep: marks_proj (blocks 0..1023) + zero accs (block 1024)
__global__ void prep_kernel(const float* __restrict__ em,
                            const float* __restrict__ Wp,
                            const float* __restrict__ bp,
                            float* __restrict__ mp,
                            float* __restrict__ accs) {
  const int b = blockIdx.x;
  if (b == 1024) {
    if (threadIdx.x < 8) accs[threadIdx.x] = 0.f;
    return;
  }
  const int d = threadIdx.x;
  float s = bp[d];
  const float* emr = em + b * 128;
#pragma unroll 4
  for (int k = 0; k < 128; ++k) s += emr[k] * Wp[k * 128 + d];
  mp[b * 128 + d] = s;
}

// ---------------- intensity: full-pair register prefetch, FORCED 2 waves/EU -
// Identical math to R10's intensity9 (passed, absmax 0). The only change:
// amdgpu_waves_per_eu(2,2) forces the allocator to use up to 256 VGPRs so the
// 128-VGPR staging array stays in registers (R10: allocator chose 128 VGPR and
// spilled 62 MB to scratch, destroying the prefetch).
__global__ __attribute__((amdgpu_flat_work_group_size(512, 512),
                          amdgpu_waves_per_eu(2, 2)))
void intensity10_kernel(
    const float* __restrict__ z_traj, const float* __restrict__ z_ev,
    const float* __restrict__ W1, const float* __restrict__ b1,
    const float* __restrict__ W2, const float* __restrict__ b2,
    const float* __restrict__ base_i, const float* __restrict__ times,
    float* __restrict__ accs) {
  __shared__ __align__(16) __bf16 w1t[512 * 128];  // 128 KB: W1^T, swizzled
  __shared__ __align__(16) float b1L[512];
  __shared__ __align__(16) float w2L[512];
  __shared__ float red[8][4];

  const int tid = threadIdx.x;
  const int wid = tid >> 6, lid = tid & 63;
  const int g = lid >> 4, q = lid & 15;
  const int gw = blockIdx.x * 8 + wid;
  const int nrounds = (gw & 1) ? 4 : 5;

  f32x4 stg[4][4][2];  // full-pair staging (64 rows), 128 VGPR

#define ZPTR(P) ((P) < 8192 ? z_traj + (size_t)(P) * 8192 \
                            : z_ev + (size_t)((P) - 8192) * 8192)
#define LOADP(ZP)                                                          \
  do {                                                                     \
    _Pragma("unroll") for (int s = 0; s < 4; ++s) {                        \
      const float* rp = (ZP) + (s * 16 + q) * 128 + g * 8;                 \
      _Pragma("unroll") for (int kf = 0; kf < 4; ++kf) {                   \
        stg[s][kf][0] = *(const f32x4*)(rp + kf * 32);                     \
        stg[s][kf][1] = *(const f32x4*)(rp + kf * 32 + 4);                 \
      }                                                                    \
    }                                                                      \
  } while (0)

  // prologue: fire round-0 loads before W staging
  LOADP(ZPTR(gw));

  // ---- one-time W1^T -> LDS (bf16, col-XOR swizzle), b1/W2 -> LDS ----
  {
    const float* wcol = W1 + tid;  // W1[k][tid], row stride 512
    char* wbs = (char*)w1t;
    const int colbase = tid * 256;
    const int sw = (tid & 7) << 4;
#pragma unroll 8
    for (int k = 0; k < 128; k += 2) {
      float a = wcol[(size_t)k * 512];
      float c = wcol[(size_t)(k + 1) * 512];
      union { __bf16 h[2]; unsigned u; } pk;
      pk.h[0] = (__bf16)a;
      pk.h[1] = (__bf16)c;
      *(unsigned*)(wbs + (colbase + ((k * 2) ^ sw))) = pk.u;
    }
    b1L[tid] = b1[tid];
    w2L[tid] = W2[tid];
  }
  const float sbias = b2[0] + base_i[0];
  barrier_lds_only();  // W ready; stg loads remain in flight

  float integral_loc = 0.f, logsum_loc = 0.f, kls = 0.f;
  const char* wb = (const char*)w1t;
  const int wsw = (q & 7) << 4;

#pragma unroll 1
  for (int r = 0; r < nrounds; ++r) {
    const bool traj_r = (r < 4);
    const int p = traj_r ? r * 2048 + gw : 8192 + (gw >> 1);

    // ---- cvt stg -> fr (+ kls) ----
    bf16x8 fr[4][4];
#pragma unroll
    for (int s = 0; s < 4; ++s) {
#pragma unroll
      for (int kf = 0; kf < 4; ++kf) {
        f32x4 a0 = stg[s][kf][0], a1 = stg[s][kf][1];
        if (traj_r) {
          kls += a0[0] * a0[0] + a0[1] * a0[1] + a0[2] * a0[2] + a0[3] * a0[3];
          kls += a1[0] * a1[0] + a1[1] * a1[1] + a1[2] * a1[2] + a1[3] * a1[3];
        }
        bf16x8 f;
#pragma unroll
        for (int j = 0; j < 4; ++j) {
          f[j] = (__bf16)a0[j];
          f[4 + j] = (__bf16)a1[j];
        }
        fr[s][kf] = f;
      }
    }

    // ---- fire next pair's 32 loads (consumed after the hidden loop) ----
    if (r + 1 < nrounds) {
      const int pn = (r + 1 < 4) ? (r + 1) * 2048 + gw : 8192 + (gw >> 1);
      const float* zn = ZPTR(pn);
      LOADP(zn);
    }
    __builtin_amdgcn_sched_barrier(0);  // pin: loads issue before hidden loop

    // ---- hidden loop: 32 c-blocks; each W-frag read feeds 4 MFMA ----
    float rowacc0 = 0.f, rowacc1 = 0.f, rowacc2 = 0.f, rowacc3 = 0.f;
#pragma unroll 2
    for (int c = 0; c < 32; ++c) {
      f32x4 a0 = {}, a1 = {}, a2 = {}, a3 = {};
#pragma unroll
      for (int kf = 0; kf < 4; ++kf) {
        bf16x8 wf = *(const bf16x8*)(wb + c * 4096 + q * 256 +
                                     ((kf * 64 + g * 16) ^ wsw));
        a0 = __builtin_amdgcn_mfma_f32_16x16x32_bf16(wf, fr[0][kf], a0, 0, 0, 0);
        a1 = __builtin_amdgcn_mfma_f32_16x16x32_bf16(wf, fr[1][kf], a1, 0, 0, 0);
        a2 = __builtin_amdgcn_mfma_f32_16x16x32_bf16(wf, fr[2][kf], a2, 0, 0, 0);
        a3 = __builtin_amdgcn_mfma_f32_16x16x32_bf16(wf, fr[3][kf], a3, 0, 0, 0);
      }
      f32x4 bb = *(const f32x4*)&b1L[c * 16 + g * 4];
      f32x4 ww = *(const f32x4*)&w2L[c * 16 + g * 4];
#pragma unroll
      for (int ii = 0; ii < 4; ++ii) {
        rowacc0 += fmaxf(a0[ii] + bb[ii], 0.f) * ww[ii];
        rowacc1 += fmaxf(a1[ii] + bb[ii], 0.f) * ww[ii];
        rowacc2 += fmaxf(a2[ii] + bb[ii], 0.f) * ww[ii];
        rowacc3 += fmaxf(a3[ii] + bb[ii], 0.f) * ww[ii];
      }
    }
    // combine 4 g-groups -> full 512-col row sums
    rowacc0 += __shfl_xor(rowacc0, 16);
    rowacc0 += __shfl_xor(rowacc0, 32);
    rowacc1 += __shfl_xor(rowacc1, 16);
    rowacc1 += __shfl_xor(rowacc1, 32);
    rowacc2 += __shfl_xor(rowacc2, 16);
    rowacc2 += __shfl_xor(rowacc2, 32);
    rowacc3 += __shfl_xor(rowacc3, 16);
    rowacc3 += __shfl_xor(rowacc3, 32);

    // lane lid owns row (p*64 + lid)
    {
      const int s = lid >> 4;
      const float rs = (s == 0) ? rowacc0 : (s == 1) ? rowacc1
                     : (s == 2) ? rowacc2 : rowacc3;
      const float lam = softplus_f(rs + sbias);
      if (traj_r) {
        integral_loc += lam * (times[p + 1] - times[p]) * (1.f / 64.f);
      } else {
        logsum_loc += logf(lam + 1e-8f) * (1.f / 64.f);
      }
    }
  }
#undef LOADP
#undef ZPTR

  // ---- wave reduce 3 accumulators, block reduce, 3 atomics ----
#pragma unroll
  for (int m = 32; m >= 1; m >>= 1) {
    integral_loc += __shfl_xor(integral_loc, m);
    logsum_loc += __shfl_xor(logsum_loc, m);
    kls += __shfl_xor(kls, m);
  }
  if (lid == 0) {
    red[wid][0] = integral_loc;
    red[wid][1] = logsum_loc;
    red[wid][2] = kls;
  }
  __syncthreads();
  if (tid == 0) {
    float I = 0.f, L = 0.f, K = 0.f;
#pragma unroll
    for (int w = 0; w < 8; ++w) {
      I += red[w][0];
      L += red[w][1];
      K += red[w][2];
    }
    atomicAdd(&accs[0], I);
    atomicAdd(&accs[1], L);
    atomicAdd(&accs[3], K);
  }
}

// ---------------- decoder: swapped GEMM1 -> h (LDS) -> swapped GEMM2 -> logp
__global__ __launch_bounds__(512, 2) void decoder2_kernel(
    const float* __restrict__ z,
    const float* __restrict__ Wd1, const float* __restrict__ bd1,
    const float* __restrict__ Wd2, const float* __restrict__ bd2,
    const float* __restrict__ mp, float* __restrict__ recon_acc) {
  __shared__ __align__(16) __bf16 zbuf[2][32 * 128];  // 16 KB
  __shared__ __align__(16) __bf16 hbuf[32 * 512];     // 32 KB
  __shared__ float s_part[32][9];
  __shared__ float red[8];

  const int tid = threadIdx.x;
  const int wid = tid >> 6, lid = tid & 63;
  const int g = lid >> 4, q = lid & 15;
  const int cb = wid * 64;
  const int tile0 = blockIdx.x * 4;

  bf16x8 bw1[4][4];
  f32x4 bd1v[4];
#pragma unroll
  for (int cf = 0; cf < 4; ++cf) {
    const int col = cb + cf * 16 + q;
#pragma unroll
    for (int i = 0; i < 4; ++i) bd1v[cf][i] = bd1[cb + cf * 16 + g * 4 + i];
#pragma unroll
    for (int kf = 0; kf < 4; ++kf) {
      bf16x8 f;
#pragma unroll
      for (int j = 0; j < 8; ++j) f[j] = (__bf16)Wd1[(kf * 32 + g * 8 + j) * 512 + col];
      bw1[cf][kf] = f;
    }
  }
  const int dimf = wid * 16 + q;
  bf16x8 bw2[16];
#pragma unroll
  for (int kf2 = 0; kf2 < 16; ++kf2) {
    bf16x8 f;
#pragma unroll
    for (int j = 0; j < 8; ++j) f[j] = (__bf16)Wd2[(kf2 * 32 + g * 8 + j) * 128 + dimf];
    bw2[kf2] = f;
  }
  f32x4 bd2v;
#pragma unroll
  for (int i = 0; i < 4; ++i) bd2v[i] = bd2[wid * 16 + g * 4 + i];

  const int srow = tid >> 4, sk8 = (tid & 15) * 8;
  const int stg_byte = ((srow * 256 + sk8 * 2) ^ ((srow & 7) << 4));
  char* hb = (char*)hbuf;

  float local = 0.f;

  {
    const float* p = z + (size_t)tile0 * 4096 + tid * 8;
    f32x4 r0 = *(const f32x4*)p, r1 = *(const f32x4*)(p + 4);
    bf16x8 v;
#pragma unroll
    for (int j = 0; j < 4; ++j) { v[j] = (__bf16)r0[j]; v[4 + j] = (__bf16)r1[j]; }
    *(bf16x8*)((char*)zbuf[0] + stg_byte) = v;
  }
  f32x4 rA0, rA1, rB0, rB1;
  { const float* p = z + (size_t)(tile0 + 1) * 4096 + tid * 8; rA0 = *(const f32x4*)p; rA1 = *(const f32x4*)(p + 4); }
  { const float* p = z + (size_t)(tile0 + 2) * 4096 + tid * 8; rB0 = *(const f32x4*)p; rB1 = *(const f32x4*)(p + 4); }
  barrier_lds_only();

#define DBODY(T, ZC, RR0, RR1)                                                     \
  do {                                                                             \
    f32x4 acc1[2][4] = {};                                                         \
    char* zc = (char*)zbuf[ZC];                                                    \
    _Pragma("unroll") for (int kf = 0; kf < 4; ++kf) {                             \
      _Pragma("unroll") for (int rf = 0; rf < 2; ++rf) {                           \
        const int row = rf * 16 + q;                                               \
        bf16x8 a = *(const bf16x8*)(zc + ((row * 256 + kf * 64 + g * 16) ^ ((row & 7) << 4))); \
        _Pragma("unroll") for (int cf = 0; cf < 4; ++cf)                           \
          acc1[rf][cf] = __builtin_amdgcn_mfma_f32_16x16x32_bf16(bw1[cf][kf], a, acc1[rf][cf], 0, 0, 0); \
      }                                                                            \
    }                                                                              \
    {                                                                              \
      bf16x8 v;                                                                    \
      _Pragma("unroll") for (int j = 0; j < 4; ++j) { v[j] = (__bf16)RR0[j]; v[4 + j] = (__bf16)RR1[j]; } \
      *(bf16x8*)((char*)zbuf[(ZC) ^ 1] + stg_byte) = v;                            \
    }                                                                              \
    {                                                                              \
      int tl = (T) + 3; if (tl > 3) tl = 3;                                        \
      const float* p = z + (size_t)(tile0 + tl) * 4096 + tid * 8;                  \
      RR0 = *(const f32x4*)p; RR1 = *(const f32x4*)(p + 4);                        \
    }                                                                              \
    _Pragma("unroll") for (int rf = 0; rf < 2; ++rf) {                             \
      const int row = rf * 16 + q;                                                 \
      _Pragma("unroll") for (int cf = 0; cf < 4; ++cf) {                           \
        bf16x4 hv;                                                                 \
        _Pragma("unroll") for (int i = 0; i < 4; ++i)                              \
          hv[i] = (__bf16)fmaxf(acc1[rf][cf][i] + bd1v[cf][i], 0.f);               \
        const int byt = ((row * 1024 + (cb + cf * 16 + g * 4) * 2) ^ ((row & 7) << 4)); \
        *(bf16x4*)(hb + byt) = hv;                                                 \
      }                                                                            \
    }                                                                              \
    barrier_lds_only();                                                            \
    f32x4 acc2[2] = {};                                                            \
    _Pragma("unroll") for (int kf2 = 0; kf2 < 16; ++kf2) {                         \
      _Pragma("unroll") for (int rf2 = 0; rf2 < 2; ++rf2) {                        \
        const int row = rf2 * 16 + q;                                              \
        bf16x8 a = *(const bf16x8*)(hb + ((row * 1024 + kf2 * 64 + g * 16) ^ ((row & 7) << 4))); \
        acc2[rf2] = __builtin_amdgcn_mfma_f32_16x16x32_bf16(bw2[kf2], a, acc2[rf2], 0, 0, 0); \
      }                                                                            \
    }                                                                              \
    const int e = (tile0 + (T)) >> 1;                                              \
    _Pragma("unroll") for (int rf2 = 0; rf2 < 2; ++rf2) {                          \
      float partial = 0.f;                                                         \
      _Pragma("unroll") for (int i = 0; i < 4; ++i) {                              \
        const float xv = mp[e * 128 + wid * 16 + g * 4 + i];                       \
        const float d = xv - (acc2[rf2][i] + bd2v[i]);                             \
        partial += d * d;                                                          \
      }                                                                            \
      partial += __shfl_xor(partial, 16);                                          \
      partial += __shfl_xor(partial, 32);                                          \
      if (lid < 16) s_part[rf2 * 16 + lid][wid] = partial;                         \
    }                                                                              \
    barrier_lds_only();                                                            \
    if (tid < 32) {                                                                \
      float t2 = 0.f;                                                              \
      _Pragma("unroll") for (int w = 0; w < 8; ++w) t2 += s_part[tid][w];          \
      local += (-0.5f * t2 - 0.5f * 128.f * LOG_2PI) * (1.f / 64.f);               \
    }                                                                              \
  } while (0)

#pragma unroll 1
  for (int t = 0; t < 4; t += 2) {
    DBODY(t, 0, rA0, rA1);
    DBODY(t + 1, 1, rB0, rB1);
  }
#undef DBODY

  if (wid == 0) {
#pragma unroll
    for (int m = 16; m >= 1; m >>= 1) local += __shfl_xor(local, m);
    if (lid == 0) atomicAdd(recon_acc, local);
  }
}

// ---------------- finalize --------------------------------------------------
__global__ void finalize_kernel(const float* __restrict__ accs, float* __restrict__ out) {
  // accs: [0]=integral, [1]=log_intensity_sum, [2]=recon, [3]=sum(z_traj^2)
  const float kl = 0.01f * (accs[3] / 67108864.f);  // 8192*64*128
  const float elbo = accs[1] - accs[0] + accs[2] - kl;
  out[0] = -elbo;
}

extern "C" void kernel_launch(void* const* d_in, const int* in_sizes, int n_in,
                              void* d_out, int out_size, void* d_ws, size_t ws_size,
                              hipStream_t stream) {
  const float* event_marks = (const float*)d_in[0];
  const float* z_events = (const float*)d_in[1];
  const float* z_traj = (const float*)d_in[2];
  const float* times = (const float*)d_in[3];
  const float* Wp = (const float*)d_in[4];
  const float* bp = (const float*)d_in[5];
  const float* W1 = (const float*)d_in[6];
  const float* b1 = (const float*)d_in[7];
  const float* W2 = (const float*)d_in[8];
  const float* b2 = (const float*)d_in[9];
  const float* base_i = (const float*)d_in[10];
  const float* Wd1 = (const float*)d_in[11];
  const float* bd1 = (const float*)d_in[12];
  const float* Wd2 = (const float*)d_in[13];
  const float* bd2 = (const float*)d_in[14];

  float* mp = (float*)d_ws;                              // 1024*128 f32
  float* accs = (float*)((char*)d_ws + 1024 * 128 * 4);  // accumulators

  prep_kernel<<<1025, 128, 0, stream>>>(event_marks, Wp, bp, mp, accs);
  intensity10_kernel<<<256, 512, 0, stream>>>(z_traj, z_events, W1, b1, W2, b2,
                                              base_i, times, accs);
  decoder2_kernel<<<512, 512, 0, stream>>>(z_events, Wd1, bd1, Wd2, bd2, mp,
                                           &accs[2]);
  finalize_kernel<<<1, 1, 0, stream>>>(accs, (float*)d_out);
}

// Round 12
// 156.188 us; speedup vs baseline: 1.2005x; 1.1962x over previous
//
#include <hip/hip_runtime.h>

typedef __attribute__((ext_vector_type(4))) float f32x4;
typedef __attribute__((ext_vector_type(8))) __bf16 bf16x8;
typedef __attribute__((ext_vector_type(4))) __bf16 bf16x4;

#define LOG_2PI 1.8378770664093453f

__device__ __forceinline__ float softplus_f(float x) {
  return fmaxf(x, 0.f) + log1pf(expf(-fabsf(x)));
}

__device__ __forceinline__ void barrier_lds_only() {
  asm volatile("s_waitcnt lgkmcnt(0)\n\ts_barrier" ::: "memory");
}

// ---------------- prep: marks_proj (blocks 0..1023) + zero accs (block 1024)
__global__ void prep_kernel(const float* __restrict__ em,
                            const float* __restrict__ Wp,
                            const float* __restrict__ bp,
                            float* __restrict__ mp,
                            float* __restrict__ accs) {
  const int b = blockIdx.x;
  if (b == 1024) {
    if (threadIdx.x < 8) accs[threadIdx.x] = 0.f;
    return;
  }
  const int d = threadIdx.x;
  float s = bp[d];
  const float* emr = em + b * 128;
#pragma unroll 4
  for (int k = 0; k < 128; ++k) s += emr[k] * Wp[k * 128 + d];
  mp[b * 128 + d] = s;
}

// ---------------- intensity: half-tile (32-row) intra-wave pipeline ---------
// 256 blocks x 12 waves = 3072 waves; wave gw owns halves [gw*6, gw*6+6) of
// 18432 32-row halves (0..16383 traj, timestep = h>>1; 16384..18431 events).
// Per round: cvt stg->fr (current half), FIRE next half's loads into stg
// (64 VGPR; consumed at next round's cvt -> in flight across the whole
// hidden loop, hiding HBM latency intra-wave and breaking the convoy), then
// hidden loop: 32 c-blocks x {1 swizzled W-frag ds_read + 2 MFMA}.
// Fits the 168-VGPR cap at 3 waves/SIMD (R10/R11: 236-VGPR plan spilled).
__global__ __launch_bounds__(768, 3) void intensity11_kernel(
    const float* __restrict__ z_traj, const float* __restrict__ z_ev,
    const float* __restrict__ W1, const float* __restrict__ b1,
    const float* __restrict__ W2, const float* __restrict__ b2,
    const float* __restrict__ base_i, const float* __restrict__ times,
    float* __restrict__ accs) {
  __shared__ __align__(16) __bf16 w1t[512 * 128];  // 128 KB: W1^T, swizzled
  __shared__ __align__(16) float b1L[512];
  __shared__ __align__(16) float w2L[512];
  __shared__ float red[12][4];

  const int tid = threadIdx.x;
  const int wid = tid >> 6, lid = tid & 63;
  const int g = lid >> 4, q = lid & 15;
  const int gw = blockIdx.x * 12 + wid;
  const int h0 = gw * 6;

  f32x4 stg[2][4][2];  // one half (32 rows) staging, 64 VGPR

#define ZROW(H) ((H) < 16384 ? z_traj + (size_t)(H) * 4096 \
                             : z_ev + (size_t)((H) - 16384) * 4096)
#define LOADH(ZP)                                                          \
  do {                                                                     \
    _Pragma("unroll") for (int s = 0; s < 2; ++s) {                        \
      const float* rp = (ZP) + (s * 16 + q) * 128 + g * 8;                 \
      _Pragma("unroll") for (int kf = 0; kf < 4; ++kf) {                   \
        stg[s][kf][0] = *(const f32x4*)(rp + kf * 32);                     \
        stg[s][kf][1] = *(const f32x4*)(rp + kf * 32 + 4);                 \
      }                                                                    \
    }                                                                      \
  } while (0)

  // prologue: fire half0 loads before W staging
  LOADH(ZROW(h0));

  // ---- one-time W1^T -> LDS (bf16, col-XOR swizzle), b1/W2 -> LDS ----
  if (tid < 512) {
    const float* wcol = W1 + tid;  // W1[k][tid], row stride 512
    char* wbs = (char*)w1t;
    const int colbase = tid * 256;
    const int sw = (tid & 7) << 4;
#pragma unroll 8
    for (int k = 0; k < 128; k += 2) {
      float a = wcol[(size_t)k * 512];
      float c = wcol[(size_t)(k + 1) * 512];
      union { __bf16 h[2]; unsigned u; } pk;
      pk.h[0] = (__bf16)a;
      pk.h[1] = (__bf16)c;
      *(unsigned*)(wbs + (colbase + ((k * 2) ^ sw))) = pk.u;
    }
    b1L[tid] = b1[tid];
    w2L[tid] = W2[tid];
  }
  const float sbias = b2[0] + base_i[0];
  barrier_lds_only();  // W ready; stg loads remain in flight

  float integral_loc = 0.f, logsum_loc = 0.f, kls = 0.f;
  const char* wb = (const char*)w1t;
  const int wsw = (q & 7) << 4;

#pragma unroll 1
  for (int r = 0; r < 6; ++r) {
    const int h = h0 + r;
    const bool traj_h = (h < 16384);

    // ---- cvt stg -> fr (+ kls) ----
    bf16x8 fr[2][4];
#pragma unroll
    for (int s = 0; s < 2; ++s) {
#pragma unroll
      for (int kf = 0; kf < 4; ++kf) {
        f32x4 a0 = stg[s][kf][0], a1 = stg[s][kf][1];
        if (traj_h) {
          kls += a0[0] * a0[0] + a0[1] * a0[1] + a0[2] * a0[2] + a0[3] * a0[3];
          kls += a1[0] * a1[0] + a1[1] * a1[1] + a1[2] * a1[2] + a1[3] * a1[3];
        }
        bf16x8 f;
#pragma unroll
        for (int j = 0; j < 4; ++j) {
          f[j] = (__bf16)a0[j];
          f[4 + j] = (__bf16)a1[j];
        }
        fr[s][kf] = f;
      }
    }

    // ---- fire next half's loads (consumed at next round's cvt) ----
    if (r < 5) LOADH(ZROW(h + 1));
    __builtin_amdgcn_sched_barrier(0);  // pin load issue before hidden loop

    // ---- hidden loop: 32 c-blocks; 1 W-frag read feeds 2 MFMA ----
    float rowacc0 = 0.f, rowacc1 = 0.f;
#pragma unroll 4
    for (int c = 0; c < 32; ++c) {
      f32x4 a0 = {}, a1 = {};
#pragma unroll
      for (int kf = 0; kf < 4; ++kf) {
        bf16x8 wf = *(const bf16x8*)(wb + c * 4096 + q * 256 +
                                     ((kf * 64 + g * 16) ^ wsw));
        a0 = __builtin_amdgcn_mfma_f32_16x16x32_bf16(wf, fr[0][kf], a0, 0, 0, 0);
        a1 = __builtin_amdgcn_mfma_f32_16x16x32_bf16(wf, fr[1][kf], a1, 0, 0, 0);
      }
      f32x4 bb = *(const f32x4*)&b1L[c * 16 + g * 4];
      f32x4 ww = *(const f32x4*)&w2L[c * 16 + g * 4];
#pragma unroll
      for (int ii = 0; ii < 4; ++ii) {
        rowacc0 += fmaxf(a0[ii] + bb[ii], 0.f) * ww[ii];
        rowacc1 += fmaxf(a1[ii] + bb[ii], 0.f) * ww[ii];
      }
    }
    // combine 4 g-groups -> full 512-col row sums
    rowacc0 += __shfl_xor(rowacc0, 16);
    rowacc0 += __shfl_xor(rowacc0, 32);
    rowacc1 += __shfl_xor(rowacc1, 16);
    rowacc1 += __shfl_xor(rowacc1, 32);

    // lane lid (<32) owns row (h*32 + lid)
    if (lid < 32) {
      const float rs = (lid < 16) ? rowacc0 : rowacc1;
      const float lam = softplus_f(rs + sbias);
      if (traj_h) {
        const int ts = h >> 1;
        integral_loc += lam * (times[ts + 1] - times[ts]) * (1.f / 64.f);
      } else {
        logsum_loc += logf(lam + 1e-8f) * (1.f / 64.f);
      }
    }
  }
#undef LOADH
#undef ZROW

  // ---- wave reduce 3 accumulators, block reduce, 3 atomics ----
#pragma unroll
  for (int m = 32; m >= 1; m >>= 1) {
    integral_loc += __shfl_xor(integral_loc, m);
    logsum_loc += __shfl_xor(logsum_loc, m);
    kls += __shfl_xor(kls, m);
  }
  if (lid == 0) {
    red[wid][0] = integral_loc;
    red[wid][1] = logsum_loc;
    red[wid][2] = kls;
  }
  __syncthreads();
  if (tid == 0) {
    float I = 0.f, L = 0.f, K = 0.f;
#pragma unroll
    for (int w = 0; w < 12; ++w) {
      I += red[w][0];
      L += red[w][1];
      K += red[w][2];
    }
    atomicAdd(&accs[0], I);
    atomicAdd(&accs[1], L);
    atomicAdd(&accs[3], K);
  }
}

// ---------------- decoder: swapped GEMM1 -> h (LDS) -> swapped GEMM2 -> logp
__global__ __launch_bounds__(512, 2) void decoder2_kernel(
    const float* __restrict__ z,
    const float* __restrict__ Wd1, const float* __restrict__ bd1,
    const float* __restrict__ Wd2, const float* __restrict__ bd2,
    const float* __restrict__ mp, float* __restrict__ recon_acc) {
  __shared__ __align__(16) __bf16 zbuf[2][32 * 128];  // 16 KB
  __shared__ __align__(16) __bf16 hbuf[32 * 512];     // 32 KB
  __shared__ float s_part[32][9];
  __shared__ float red[8];

  const int tid = threadIdx.x;
  const int wid = tid >> 6, lid = tid & 63;
  const int g = lid >> 4, q = lid & 15;
  const int cb = wid * 64;
  const int tile0 = blockIdx.x * 4;

  bf16x8 bw1[4][4];
  f32x4 bd1v[4];
#pragma unroll
  for (int cf = 0; cf < 4; ++cf) {
    const int col = cb + cf * 16 + q;
#pragma unroll
    for (int i = 0; i < 4; ++i) bd1v[cf][i] = bd1[cb + cf * 16 + g * 4 + i];
#pragma unroll
    for (int kf = 0; kf < 4; ++kf) {
      bf16x8 f;
#pragma unroll
      for (int j = 0; j < 8; ++j) f[j] = (__bf16)Wd1[(kf * 32 + g * 8 + j) * 512 + col];
      bw1[cf][kf] = f;
    }
  }
  const int dimf = wid * 16 + q;
  bf16x8 bw2[16];
#pragma unroll
  for (int kf2 = 0; kf2 < 16; ++kf2) {
    bf16x8 f;
#pragma unroll
    for (int j = 0; j < 8; ++j) f[j] = (__bf16)Wd2[(kf2 * 32 + g * 8 + j) * 128 + dimf];
    bw2[kf2] = f;
  }
  f32x4 bd2v;
#pragma unroll
  for (int i = 0; i < 4; ++i) bd2v[i] = bd2[wid * 16 + g * 4 + i];

  const int srow = tid >> 4, sk8 = (tid & 15) * 8;
  const int stg_byte = ((srow * 256 + sk8 * 2) ^ ((srow & 7) << 4));
  char* hb = (char*)hbuf;

  float local = 0.f;

  {
    const float* p = z + (size_t)tile0 * 4096 + tid * 8;
    f32x4 r0 = *(const f32x4*)p, r1 = *(const f32x4*)(p + 4);
    bf16x8 v;
#pragma unroll
    for (int j = 0; j < 4; ++j) { v[j] = (__bf16)r0[j]; v[4 + j] = (__bf16)r1[j]; }
    *(bf16x8*)((char*)zbuf[0] + stg_byte) = v;
  }
  f32x4 rA0, rA1, rB0, rB1;
  { const float* p = z + (size_t)(tile0 + 1) * 4096 + tid * 8; rA0 = *(const f32x4*)p; rA1 = *(const f32x4*)(p + 4); }
  { const float* p = z + (size_t)(tile0 + 2) * 4096 + tid * 8; rB0 = *(const f32x4*)p; rB1 = *(const f32x4*)(p + 4); }
  barrier_lds_only();

#define DBODY(T, ZC, RR0, RR1)                                                     \
  do {                                                                             \
    f32x4 acc1[2][4] = {};                                                         \
    char* zc = (char*)zbuf[ZC];                                                    \
    _Pragma("unroll") for (int kf = 0; kf < 4; ++kf) {                             \
      _Pragma("unroll") for (int rf = 0; rf < 2; ++rf) {                           \
        const int row = rf * 16 + q;                                               \
        bf16x8 a = *(const bf16x8*)(zc + ((row * 256 + kf * 64 + g * 16) ^ ((row & 7) << 4))); \
        _Pragma("unroll") for (int cf = 0; cf < 4; ++cf)                           \
          acc1[rf][cf] = __builtin_amdgcn_mfma_f32_16x16x32_bf16(bw1[cf][kf], a, acc1[rf][cf], 0, 0, 0); \
      }                                                                            \
    }                                                                              \
    {                                                                              \
      bf16x8 v;                                                                    \
      _Pragma("unroll") for (int j = 0; j < 4; ++j) { v[j] = (__bf16)RR0[j]; v[4 + j] = (__bf16)RR1[j]; } \
      *(bf16x8*)((char*)zbuf[(ZC) ^ 1] + stg_byte) = v;                            \
    }                                                                              \
    {                                                                              \
      int tl = (T) + 3; if (tl > 3) tl = 3;                                        \
      const float* p = z + (size_t)(tile0 + tl) * 4096 + tid * 8;                  \
      RR0 = *(const f32x4*)p; RR1 = *(const f32x4*)(p + 4);                        \
    }                                                                              \
    _Pragma("unroll") for (int rf = 0; rf < 2; ++rf) {                             \
      const int row = rf * 16 + q;                                                 \
      _Pragma("unroll") for (int cf = 0; cf < 4; ++cf) {                           \
        bf16x4 hv;                                                                 \
        _Pragma("unroll") for (int i = 0; i < 4; ++i)                              \
          hv[i] = (__bf16)fmaxf(acc1[rf][cf][i] + bd1v[cf][i], 0.f);               \
        const int byt = ((row * 1024 + (cb + cf * 16 + g * 4) * 2) ^ ((row & 7) << 4)); \
        *(bf16x4*)(hb + byt) = hv;                                                 \
      }                                                                            \
    }                                                                              \
    barrier_lds_only();                                                            \
    f32x4 acc2[2] = {};                                                            \
    _Pragma("unroll") for (int kf2 = 0; kf2 < 16; ++kf2) {                         \
      _Pragma("unroll") for (int rf2 = 0; rf2 < 2; ++rf2) {                        \
        const int row = rf2 * 16 + q;                                              \
        bf16x8 a = *(const bf16x8*)(hb + ((row * 1024 + kf2 * 64 + g * 16) ^ ((row & 7) << 4))); \
        acc2[rf2] = __builtin_amdgcn_mfma_f32_16x16x32_bf16(bw2[kf2], a, acc2[rf2], 0, 0, 0); \
      }                                                                            \
    }                                                                              \
    const int e = (tile0 + (T)) >> 1;                                              \
    _Pragma("unroll") for (int rf2 = 0; rf2 < 2; ++rf2) {                          \
      float partial = 0.f;                                                         \
      _Pragma("unroll") for (int i = 0; i < 4; ++i) {                              \
        const float xv = mp[e * 128 + wid * 16 + g * 4 + i];                       \
        const float d = xv - (acc2[rf2][i] + bd2v[i]);                             \
        partial += d * d;                                                          \
      }                                                                            \
      partial += __shfl_xor(partial, 16);                                          \
      partial += __shfl_xor(partial, 32);                                          \
      if (lid < 16) s_part[rf2 * 16 + lid][wid] = partial;                         \
    }                                                                              \
    barrier_lds_only();                                                            \
    if (tid < 32) {                                                                \
      float t2 = 0.f;                                                              \
      _Pragma("unroll") for (int w = 0; w < 8; ++w) t2 += s_part[tid][w];          \
      local += (-0.5f * t2 - 0.5f * 128.f * LOG_2PI) * (1.f / 64.f);               \
    }                                                                              \
  } while (0)

#pragma unroll 1
  for (int t = 0; t < 4; t += 2) {
    DBODY(t, 0, rA0, rA1);
    DBODY(t + 1, 1, rB0, rB1);
  }
#undef DBODY

  if (wid == 0) {
#pragma unroll
    for (int m = 16; m >= 1; m >>= 1) local += __shfl_xor(local, m);
    if (lid == 0) atomicAdd(recon_acc, local);
  }
}

// ---------------- finalize --------------------------------------------------
__global__ void finalize_kernel(const float* __restrict__ accs, float* __restrict__ out) {
  // accs: [0]=integral, [1]=log_intensity_sum, [2]=recon, [3]=sum(z_traj^2)
  const float kl = 0.01f * (accs[3] / 67108864.f);  // 8192*64*128
  const float elbo = accs[1] - accs[0] + accs[2] - kl;
  out[0] = -elbo;
}

extern "C" void kernel_launch(void* const* d_in, const int* in_sizes, int n_in,
                              void* d_out, int out_size, void* d_ws, size_t ws_size,
                              hipStream_t stream) {
  const float* event_marks = (const float*)d_in[0];
  const float* z_events = (const float*)d_in[1];
  const float* z_traj = (const float*)d_in[2];
  const float* times = (const float*)d_in[3];
  const float* Wp = (const float*)d_in[4];
  const float* bp = (const float*)d_in[5];
  const float* W1 = (const float*)d_in[6];
  const float* b1 = (const float*)d_in[7];
  const float* W2 = (const float*)d_in[8];
  const float* b2 = (const float*)d_in[9];
  const float* base_i = (const float*)d_in[10];
  const float* Wd1 = (const float*)d_in[11];
  const float* bd1 = (const float*)d_in[12];
  const float* Wd2 = (const float*)d_in[13];
  const float* bd2 = (const float*)d_in[14];

  float* mp = (float*)d_ws;                              // 1024*128 f32
  float* accs = (float*)((char*)d_ws + 1024 * 128 * 4);  // accumulators

  prep_kernel<<<1025, 128, 0, stream>>>(event_marks, Wp, bp, mp, accs);
  intensity11_kernel<<<256, 768, 0, stream>>>(z_traj, z_events, W1, b1, W2, b2,
                                              base_i, times, accs);
  decoder2_kernel<<<512, 512, 0, stream>>>(z_events, Wd1, bd1, Wd2, bd2, mp,
                                           &accs[2]);
  finalize_kernel<<<1, 1, 0, stream>>>(accs, (float*)d_out);
}